// Round 5
// baseline (512.013 us; speedup 1.0000x reference)
//
#include <hip/hip_runtime.h>
#include <hip/hip_bf16.h>
#include <stdint.h>

// Problem constants
#define B_   32
#define N_   480
#define DIM_ 1024
#define H_   16
#define D_   64
#define M_   (B_*N_)   // 15360
#define BH_  (B_*H_)   // 512

typedef __bf16 bf16;
typedef __bf16 bf16x4 __attribute__((ext_vector_type(4)));
typedef __bf16 bf16x8 __attribute__((ext_vector_type(8)));
typedef short  short4v __attribute__((ext_vector_type(4)));
typedef float  f32x4  __attribute__((ext_vector_type(4)));

// async global->LDS, 16B per lane; LDS dest = wave-uniform base + lane*16
__device__ __forceinline__ void gld_lds16(const void* g, void* l) {
    using GP = const __attribute__((address_space(1))) unsigned int*;
    using LP = __attribute__((address_space(3))) unsigned int*;
    __builtin_amdgcn_global_load_lds((GP)(uintptr_t)g, (LP)(unsigned int)(uintptr_t)l, 16, 0, 0);
}

// ---------------- fp32 -> bf16 converts ----------------
__global__ void cvt4(const float* __restrict__ in, bf16* __restrict__ out, int n4) {
    int i = blockIdx.x * 256 + threadIdx.x;
    if (i >= n4) return;
    float4 v = ((const float4*)in)[i];
    bf16x4 o = { (bf16)v.x, (bf16)v.y, (bf16)v.z, (bf16)v.w };
    ((bf16x4*)out)[i] = o;
}

__global__ void cvtW(const float* __restrict__ Wq, const float* __restrict__ Wk,
                     const float* __restrict__ Wv, const float* __restrict__ Wo,
                     bf16* __restrict__ Wcat, bf16* __restrict__ Wob) {
    int i = blockIdx.x * 256 + threadIdx.x;
    const float* src; bf16* dst;
    switch (blockIdx.y) {
        case 0: src = Wq; dst = Wcat;                break;
        case 1: src = Wk; dst = Wcat + DIM_*DIM_;    break;
        case 2: src = Wv; dst = Wcat + 2*DIM_*DIM_;  break;
        default: src = Wo; dst = Wob;                break;
    }
    float4 v = ((const float4*)src)[i];
    bf16x4 o = { (bf16)v.x, (bf16)v.y, (bf16)v.z, (bf16)v.w };
    ((bf16x4*)dst)[i] = o;
}

// ======== shared GEMM core: 128x128 tile, BK=64, XOR-swizzled LDS ========
// LDS layout: row r (128B = 8 chunks of 16B); logical chunk c stored at
// physical slot c^(r&7). global_load_lds writes lane->slot `lane` of an
// 8-row group, so lane fetches global chunk (lane&7)^((lane>>3)&7) of row
// (lane>>3). ds_read_b128 fragment reads then hit all 32 banks 2-way (free).
#define GEMM_PRE()                                                            \
    const int tid  = threadIdx.x;                                             \
    const int lane = tid & 63;                                                \
    const int wid  = tid >> 6;                                                \
    const int wm   = wid & 1, wn = wid >> 1;                                  \
    const int m0   = blockIdx.y * 128;                                        \
    const int n0   = blockIdx.x * 128;                                        \
    const int lm   = lane & 15, lq = lane >> 4;                               \
    const int aLane = (lane >> 3) * 1024 + (((lane & 7) ^ (lane >> 3)) & 7) * 8; \
    const bf16* Asrc = A  + (m0 + wid*32) * 1024 + aLane;                     \
    const bf16* Bsrc = Bw + (n0 + wid*32) * 1024 + aLane;                     \
    bf16* AsDst = As + (wid*32)*64;                                           \
    bf16* BsDst = Bs + (wid*32)*64;                                           \
    int rowA[4], rowB[4];                                                     \
    _Pragma("unroll") for (int m = 0; m < 4; ++m) rowA[m] = (wm*64 + m*16 + lm)*64; \
    _Pragma("unroll") for (int n = 0; n < 4; ++n) rowB[n] = (wn*64 + n*16 + lm)*64; \
    const int sw = lm & 7;                                                    \
    int phys[2];                                                              \
    phys[0] = ((lq)     ^ sw) * 8;                                            \
    phys[1] = ((4 + lq) ^ sw) * 8;

#define GEMM_KLOOP(FIRST, SECOND)                                             \
    for (int k0 = 0; k0 < 1024; k0 += 64) {                                   \
        _Pragma("unroll") for (int j = 0; j < 4; ++j) {                       \
            gld_lds16(Asrc + k0 + j*8192, AsDst + j*512);                     \
            gld_lds16(Bsrc + k0 + j*8192, BsDst + j*512);                     \
        }                                                                     \
        __syncthreads();                                                      \
        _Pragma("unroll") for (int ks = 0; ks < 2; ++ks) {                    \
            bf16x8 af[4], bfr[4];                                             \
            _Pragma("unroll") for (int m = 0; m < 4; ++m)                     \
                af[m]  = *(const bf16x8*)&As[rowA[m] + phys[ks]];             \
            _Pragma("unroll") for (int n = 0; n < 4; ++n)                     \
                bfr[n] = *(const bf16x8*)&Bs[rowB[n] + phys[ks]];             \
            _Pragma("unroll") for (int m = 0; m < 4; ++m)                     \
                _Pragma("unroll") for (int n = 0; n < 4; ++n)                 \
                    acc[m][n] = __builtin_amdgcn_mfma_f32_16x16x32_bf16(      \
                        FIRST, SECOND, acc[m][n], 0, 0, 0);                   \
        }                                                                     \
        __syncthreads();                                                      \
    }

// ---------------- QKV projection GEMM ----------------
// C[m,gn] = sum_k A[m,k]*Wcat[gn,k]; Q,K -> [bh][n][d]; V -> [bh][d][n].
// V blocks use swapped MFMA operands (compute C^T) so the transposed store
// is lane-contiguous along n.
__global__ __launch_bounds__(256) void gemm_qkv(const bf16* __restrict__ A, const bf16* __restrict__ Bw,
                                                bf16* __restrict__ Qp, bf16* __restrict__ Kp,
                                                bf16* __restrict__ Vt) {
    __shared__ bf16 As[128*64];
    __shared__ bf16 Bs[128*64];
    GEMM_PRE();
    const int part = n0 >> 10;  // 0=Q,1=K,2=V (block-uniform)
    f32x4 acc[4][4] = {};

    if (part != 2) {
        GEMM_KLOOP(af[m], bfr[n]);
        // C layout: col(gn)=lm, row(gm)=lq*4+r
        bf16* dst = (part == 0) ? Qp : Kp;
        int hh[4], dd[4];
#pragma unroll
        for (int n = 0; n < 4; ++n) {
            int rem = (n0 + wn*64 + n*16 + lm) & 1023;
            hh[n] = rem >> 6; dd[n] = rem & 63;
        }
#pragma unroll
        for (int m = 0; m < 4; ++m) {
#pragma unroll
            for (int r = 0; r < 4; ++r) {
                int gm = m0 + wm*64 + m*16 + lq*4 + r;
                int b  = gm / 480;
                int nn = gm - b*480;
#pragma unroll
                for (int n = 0; n < 4; ++n)
                    dst[((b*16 + hh[n])*480 + nn)*64 + dd[n]] = (bf16)acc[m][n][r];
            }
        }
    } else {
        GEMM_KLOOP(bfr[n], af[m]);
        // C^T layout: col(gm)=lm, row(gn)=lq*4+r -> stores contiguous in nn
#pragma unroll
        for (int m = 0; m < 4; ++m) {
            int gmBase = m0 + wm*64 + m*16;      // lane-uniform; 480%16==0 -> b uniform
            int b  = gmBase / 480;
            int nn = gmBase - b*480 + lm;
#pragma unroll
            for (int n = 0; n < 4; ++n)
#pragma unroll
                for (int r = 0; r < 4; ++r) {
                    int rem = (n0 + wn*64 + n*16 + lq*4 + r) & 1023;
                    int h = rem >> 6, d = rem & 63;
                    Vt[((b*16 + h)*64 + d)*480 + nn] = (bf16)acc[m][n][r];
                }
        }
    }
}

// ---------------- fused attention v7 ----------------
// v6 post-mortem: spill fixed (WRITE 320->31MB) but OccupancyPercent fell to
// 16.8% (57KB LDS -> 2 blocks/CU) and all pipes sat <23% -> latency-bound
// with nothing resident. v7 keeps the async-DMA double-buffer structure but
// quarters the tile: KT=48, LDS = 2x6KB (Ks) + 2x8KB (Vs) = 28672 B ->
// 5 blocks/CU by LDS, 24-30 resident waves. launch_bounds(384,6) caps VGPR
// at 85 (v6 used 84; deliberately NOT 8 waves -> no spill regression).
//  * K tile: 48 rows x 128B = 6 windows; wave wid stages window wid.
//  * V tile: 64 d-rows x 8 chunks (6 real + 2 pad clamped to chunk 5, L2
//    dup); 8 windows: wave wid stages window wid, waves 0..1 also wid+6.
//  * Per iter: barrier -> pe4[3] loads (BEFORE DMAs so pe's vmcnt wait
//    leaves DMAs in flight) -> STAGE(kt+1, buf^1) -> compute buf.
#define KT 48
#define OS_LD 72
__global__ __launch_bounds__(384, 6) void attn(const bf16* __restrict__ Qp, const bf16* __restrict__ Kp,
                                               const bf16* __restrict__ Vt, const float* __restrict__ pe,
                                               bf16* __restrict__ O) {
    __shared__ bf16 Ks[2][KT*64];    // 2 x 6144 B
    __shared__ bf16 Vs[2][64*64];    // 2 x 8192 B
    const int tid  = threadIdx.x;
    const int lane = tid & 63, wid = tid >> 6;   // 6 waves
    const int bh   = blockIdx.y;
    const int b    = bh >> 4, h = bh & 15;
    const int qblk = blockIdx.x * 96;
    const int lm   = lane & 15, lq = lane >> 4;
    const int qbase = bh * (N_ * 64);

    // K staging: window = 8 rows x 8 chunks; lane -> row lane>>3, phys chunk
    // lane&7, fetched logical chunk (lane&7)^(lane>>3).
    const int kROff = (lane >> 3)*64 + ((lane & 7) ^ (lane >> 3))*8;
    // V staging: same lane pattern, logical chunk clamped to 5 (pad slots
    // duplicate chunk 5; readers never map logical c<=5 to a pad slot).
    int cV = (lane & 7) ^ (lane >> 3);
    if (cV > 5) cV = 5;
    int vOffG[2];
#pragma unroll
    for (int i = 0; i < 2; ++i) {
        int j = wid + 6*i;                       // window 0..7 (i=1 only wid<2)
        vOffG[i] = (bh*64 + j*8 + (lane >> 3))*480 + cV*8;
    }

    // Q fragments (B operand): n=q=lm, k=d
    bf16x8 qb[2];
#pragma unroll
    for (int ks = 0; ks < 2; ++ks)
        qb[ks] = *(const bf16x8*)&Qp[qbase + (qblk + wid*16 + lm)*64 + ks*32 + lq*8];
    const float* peP = pe + (qblk + wid*16 + lm)*480 + lq*4;

    // fragment LDS byte offsets (swizzle folded in)
    int kOff[2];
#pragma unroll
    for (int ks = 0; ks < 2; ++ks) kOff[ks] = ((ks*4 + lq) ^ (lm & 7)) << 4;
    int vOff[3];
#pragma unroll
    for (int mf = 0; mf < 3; ++mf) {
        int c = 2*mf + (lq >> 1);                // logical chunk 0..5
        vOff[mf] = ((c ^ (lm & 7)) << 4) + (lq & 1)*8;
    }

#define STAGE(T, BUF)                                                         \
    {   gld_lds16(Kp + qbase + (T)*(KT*64) + wid*512 + kROff,                 \
                  (char*)Ks[BUF] + wid*1024);                                 \
        gld_lds16(Vt + vOffG[0] + (T)*KT, (char*)Vs[BUF] + wid*1024);         \
        if (wid < 2)                                                          \
            gld_lds16(Vt + vOffG[1] + (T)*KT, (char*)Vs[BUF] + (wid+6)*1024); }

    STAGE(0, 0);

    f32x4 ot[4] = {};      // O^T accum: m=d (4 frags), n=q
    float lsum = 0.f;

    for (int kt = 0; kt < 10; ++kt) {
        const int cur = kt & 1;
        __syncthreads();                       // drains tile-kt DMA (issued a full phase ago)
        // pe loads first (older than DMAs in vmcnt order -> their waits can't drain DMAs)
        f32x4 pe4[3];
#pragma unroll
        for (int mf = 0; mf < 3; ++mf)
            pe4[mf] = *(const f32x4*)(peP + kt*KT + mf*16);
        if (kt < 9) STAGE(kt + 1, cur ^ 1);    // latency hides under compute
        const char* KsB = (const char*)Ks[cur];
        const char* VsB = (const char*)Vs[cur];

        // S^T = K Q^T; P^T = exp(scale*S^T + pe) packed as 16x16x16 B-frags
        short4v pb[3];
#pragma unroll
        for (int mf = 0; mf < 3; ++mf) {
            f32x4 s = {};
#pragma unroll
            for (int ks = 0; ks < 2; ++ks) {
                bf16x8 ka = *(const bf16x8*)(KsB + (mf*16 + lm)*128 + kOff[ks]);
                s = __builtin_amdgcn_mfma_f32_16x16x32_bf16(ka, qb[ks], s, 0, 0, 0);
            }
            bf16x4 pv;
#pragma unroll
            for (int r = 0; r < 4; ++r) {
                float e = __expf(s[r] * 0.125f + pe4[mf][r]);
                lsum += e;
                pv[r] = (bf16)e;
            }
            pb[mf] = __builtin_bit_cast(short4v, pv);
        }

        // O^T += V^T P^T via 16x16x16 (A = V frags from swizzled Vs rows)
#pragma unroll
        for (int df = 0; df < 4; ++df) {
            const char* vrow = VsB + (df*16 + lm)*128;
#pragma unroll
            for (int mf = 0; mf < 3; ++mf) {
                short4v va = *(const short4v*)(vrow + vOff[mf]);
                ot[df] = __builtin_amdgcn_mfma_f32_16x16x16bf16_1k(va, pb[mf], ot[df], 0, 0, 0);
            }
        }
    }
#undef STAGE

    // softmax denom across the 4 lane-groups holding q=lm
    lsum += __shfl_xor(lsum, 16);
    lsum += __shfl_xor(lsum, 32);
    float rl = 1.f / lsum;

    // transpose O^T -> O via LDS (reuse Vs region: 96*72*2 = 13824 <= 16384)
    __syncthreads();
    bf16* Os = &Vs[0][0];  // [96 q][OS_LD]
#pragma unroll
    for (int df = 0; df < 4; ++df)
#pragma unroll
        for (int r = 0; r < 4; ++r)
            Os[(wid*16 + lm)*OS_LD + df*16 + lq*4 + r] = (bf16)(ot[df][r] * rl);
    __syncthreads();
    for (int c = tid; c < 768; c += 384) {
        int row = c >> 3, d0 = (c & 7) * 8;
        uint4 u = *(const uint4*)&Os[row*OS_LD + d0];
        *(uint4*)&O[(b*480 + qblk + row)*1024 + h*64 + d0] = u;
    }
}

// ---------------- output projection GEMM + bias ----------------
__global__ __launch_bounds__(256) void gemm_out(const bf16* __restrict__ A, const bf16* __restrict__ Bw,
                                                const float* __restrict__ bo, float* __restrict__ out) {
    __shared__ bf16 As[128*64];
    __shared__ bf16 Bs[128*64];
    GEMM_PRE();
    f32x4 acc[4][4] = {};
    GEMM_KLOOP(af[m], bfr[n]);
#pragma unroll
    for (int m = 0; m < 4; ++m)
#pragma unroll
        for (int n = 0; n < 4; ++n)
#pragma unroll
            for (int r = 0; r < 4; ++r) {
                int gm = m0 + wm*64 + m*16 + lq*4 + r;
                int gn = n0 + wn*64 + n*16 + lm;
                out[gm*1024 + gn] = acc[m][n][r] + bo[gn];
            }
}

// ---------------- launcher ----------------
extern "C" void kernel_launch(void* const* d_in, const int* in_sizes, int n_in,
                              void* d_out, int out_size, void* d_ws, size_t ws_size,
                              hipStream_t stream) {
    const float* q  = (const float*)d_in[0];
    const float* Wq = (const float*)d_in[1];
    const float* Wk = (const float*)d_in[2];
    const float* Wv = (const float*)d_in[3];
    const float* pe = (const float*)d_in[4];
    const float* Wo = (const float*)d_in[5];
    const float* bo = (const float*)d_in[6];
    float* out = (float*)d_out;

    char* ws = (char*)d_ws;
    bf16* Abf  = (bf16*)(ws);                         // q bf16 (M x 1024); reused as attn O buffer
    bf16* Wcat = (bf16*)(ws + 31457280);              // 3072 x 1024
    bf16* Wob  = (bf16*)(ws + 31457280 + 6291456);    // 1024 x 1024
    bf16* Qp   = (bf16*)(ws + 39845888);              // [bh][n][d]
    bf16* Kp   = (bf16*)(ws + 71303168);              // [bh][n][d]
    bf16* Vt   = (bf16*)(ws + 102760448);             // [bh][d][n]

    cvt4<<<(M_*DIM_/4 + 255)/256, 256, 0, stream>>>(q, Abf, M_*DIM_/4);
    cvtW<<<dim3(DIM_*DIM_/4/256, 4), 256, 0, stream>>>(Wq, Wk, Wv, Wo, Wcat, Wob);

    gemm_qkv<<<dim3(24, 120), 256, 0, stream>>>(Abf, Wcat, Qp, Kp, Vt);
    attn<<<dim3(5, 512), 384, 0, stream>>>(Qp, Kp, Vt, pe, Abf);
    gemm_out<<<dim3(8, 120), 256, 0, stream>>>(Abf, Wob, bo, out);
}

// Round 6
// 425.260 us; speedup vs baseline: 1.2040x; 1.2040x over previous
//
#include <hip/hip_runtime.h>
#include <hip/hip_bf16.h>
#include <stdint.h>

// Problem constants
#define B_   32
#define N_   480
#define DIM_ 1024
#define H_   16
#define D_   64
#define M_   (B_*N_)   // 15360
#define BH_  (B_*H_)   // 512

typedef __bf16 bf16;
typedef __bf16 bf16x4 __attribute__((ext_vector_type(4)));
typedef __bf16 bf16x8 __attribute__((ext_vector_type(8)));
typedef short  short4v __attribute__((ext_vector_type(4)));
typedef float  f32x4  __attribute__((ext_vector_type(4)));

// async global->LDS, 16B per lane; LDS dest = wave-uniform base + lane*16
__device__ __forceinline__ void gld_lds16(const void* g, void* l) {
    using GP = const __attribute__((address_space(1))) unsigned int*;
    using LP = __attribute__((address_space(3))) unsigned int*;
    __builtin_amdgcn_global_load_lds((GP)(uintptr_t)g, (LP)(unsigned int)(uintptr_t)l, 16, 0, 0);
}

// ---------------- fp32 -> bf16 converts ----------------
__global__ void cvt4(const float* __restrict__ in, bf16* __restrict__ out, int n4) {
    int i = blockIdx.x * 256 + threadIdx.x;
    if (i >= n4) return;
    float4 v = ((const float4*)in)[i];
    bf16x4 o = { (bf16)v.x, (bf16)v.y, (bf16)v.z, (bf16)v.w };
    ((bf16x4*)out)[i] = o;
}

__global__ void cvtW(const float* __restrict__ Wq, const float* __restrict__ Wk,
                     const float* __restrict__ Wv, const float* __restrict__ Wo,
                     bf16* __restrict__ Wcat, bf16* __restrict__ Wob) {
    int i = blockIdx.x * 256 + threadIdx.x;
    const float* src; bf16* dst;
    switch (blockIdx.y) {
        case 0: src = Wq; dst = Wcat;                break;
        case 1: src = Wk; dst = Wcat + DIM_*DIM_;    break;
        case 2: src = Wv; dst = Wcat + 2*DIM_*DIM_;  break;
        default: src = Wo; dst = Wob;                break;
    }
    float4 v = ((const float4*)src)[i];
    bf16x4 o = { (bf16)v.x, (bf16)v.y, (bf16)v.z, (bf16)v.w };
    ((bf16x4*)dst)[i] = o;
}

// ======== shared GEMM core: 128x128 tile, BK=64, XOR-swizzled LDS ========
// LDS layout: row r (128B = 8 chunks of 16B); logical chunk c stored at
// physical slot c^(r&7). global_load_lds writes lane->slot `lane` of an
// 8-row group, so lane fetches global chunk (lane&7)^((lane>>3)&7) of row
// (lane>>3). ds_read_b128 fragment reads then hit all 32 banks 2-way (free).
#define GEMM_PRE()                                                            \
    const int tid  = threadIdx.x;                                             \
    const int lane = tid & 63;                                                \
    const int wid  = tid >> 6;                                                \
    const int wm   = wid & 1, wn = wid >> 1;                                  \
    const int m0   = blockIdx.y * 128;                                        \
    const int n0   = blockIdx.x * 128;                                        \
    const int lm   = lane & 15, lq = lane >> 4;                               \
    const int aLane = (lane >> 3) * 1024 + (((lane & 7) ^ (lane >> 3)) & 7) * 8; \
    const bf16* Asrc = A  + (m0 + wid*32) * 1024 + aLane;                     \
    const bf16* Bsrc = Bw + (n0 + wid*32) * 1024 + aLane;                     \
    bf16* AsDst = As + (wid*32)*64;                                           \
    bf16* BsDst = Bs + (wid*32)*64;                                           \
    int rowA[4], rowB[4];                                                     \
    _Pragma("unroll") for (int m = 0; m < 4; ++m) rowA[m] = (wm*64 + m*16 + lm)*64; \
    _Pragma("unroll") for (int n = 0; n < 4; ++n) rowB[n] = (wn*64 + n*16 + lm)*64; \
    const int sw = lm & 7;                                                    \
    int phys[2];                                                              \
    phys[0] = ((lq)     ^ sw) * 8;                                            \
    phys[1] = ((4 + lq) ^ sw) * 8;

#define GEMM_KLOOP(FIRST, SECOND)                                             \
    for (int k0 = 0; k0 < 1024; k0 += 64) {                                   \
        _Pragma("unroll") for (int j = 0; j < 4; ++j) {                       \
            gld_lds16(Asrc + k0 + j*8192, AsDst + j*512);                     \
            gld_lds16(Bsrc + k0 + j*8192, BsDst + j*512);                     \
        }                                                                     \
        __syncthreads();                                                      \
        _Pragma("unroll") for (int ks = 0; ks < 2; ++ks) {                    \
            bf16x8 af[4], bfr[4];                                             \
            _Pragma("unroll") for (int m = 0; m < 4; ++m)                     \
                af[m]  = *(const bf16x8*)&As[rowA[m] + phys[ks]];             \
            _Pragma("unroll") for (int n = 0; n < 4; ++n)                     \
                bfr[n] = *(const bf16x8*)&Bs[rowB[n] + phys[ks]];             \
            _Pragma("unroll") for (int m = 0; m < 4; ++m)                     \
                _Pragma("unroll") for (int n = 0; n < 4; ++n)                 \
                    acc[m][n] = __builtin_amdgcn_mfma_f32_16x16x32_bf16(      \
                        FIRST, SECOND, acc[m][n], 0, 0, 0);                   \
        }                                                                     \
        __syncthreads();                                                      \
    }

// ---------------- QKV projection GEMM ----------------
// C[m,gn] = sum_k A[m,k]*Wcat[gn,k]; Q,K -> [bh][n][d]; V -> [bh][d][n].
// V blocks use swapped MFMA operands (compute C^T) so the transposed store
// is lane-contiguous along n.
__global__ __launch_bounds__(256) void gemm_qkv(const bf16* __restrict__ A, const bf16* __restrict__ Bw,
                                                bf16* __restrict__ Qp, bf16* __restrict__ Kp,
                                                bf16* __restrict__ Vt) {
    __shared__ bf16 As[128*64];
    __shared__ bf16 Bs[128*64];
    GEMM_PRE();
    const int part = n0 >> 10;  // 0=Q,1=K,2=V (block-uniform)
    f32x4 acc[4][4] = {};

    if (part != 2) {
        GEMM_KLOOP(af[m], bfr[n]);
        // C layout: col(gn)=lm, row(gm)=lq*4+r
        bf16* dst = (part == 0) ? Qp : Kp;
        int hh[4], dd[4];
#pragma unroll
        for (int n = 0; n < 4; ++n) {
            int rem = (n0 + wn*64 + n*16 + lm) & 1023;
            hh[n] = rem >> 6; dd[n] = rem & 63;
        }
#pragma unroll
        for (int m = 0; m < 4; ++m) {
#pragma unroll
            for (int r = 0; r < 4; ++r) {
                int gm = m0 + wm*64 + m*16 + lq*4 + r;
                int b  = gm / 480;
                int nn = gm - b*480;
#pragma unroll
                for (int n = 0; n < 4; ++n)
                    dst[((b*16 + hh[n])*480 + nn)*64 + dd[n]] = (bf16)acc[m][n][r];
            }
        }
    } else {
        GEMM_KLOOP(bfr[n], af[m]);
        // C^T layout: col(gm)=lm, row(gn)=lq*4+r -> stores contiguous in nn
#pragma unroll
        for (int m = 0; m < 4; ++m) {
            int gmBase = m0 + wm*64 + m*16;      // lane-uniform; 480%16==0 -> b uniform
            int b  = gmBase / 480;
            int nn = gmBase - b*480 + lm;
#pragma unroll
            for (int n = 0; n < 4; ++n)
#pragma unroll
                for (int r = 0; r < 4; ++r) {
                    int rem = (n0 + wn*64 + n*16 + lq*4 + r) & 1023;
                    int h = rem >> 6, d = rem & 63;
                    Vt[((b*16 + h)*64 + d)*480 + nn] = (bf16)acc[m][n][r];
                }
        }
    }
}

// ---------------- fused attention v8 ----------------
// v7 post-mortem: launch_bounds(384,6) made the allocator squeeze to 40 VGPR
// (below the ~60-70 the loop needs) -> ~300B/thread scratch spill every tile
// (WRITE 31->330MB, FETCH +150MB fills). The KT=48 geometry itself was good
// (occupancy 16.8->43%). v8 = v7 geometry + v6's PROVEN register policy
// launch_bounds(384,3): v6's bigger loop allocated 84 VGPR spill-free under
// it, and 84 VGPR still yields 6 waves/EU = 24 waves/CU (4 blocks, LDS
// allows 5). Single-variable change vs v7.
//  * K tile: 48 rows x 128B = 6 windows; wave wid stages window wid.
//  * V tile: 64 d-rows x 8 chunks (6 real + 2 pad clamped to chunk 5, L2
//    dup); 8 windows: wave wid stages window wid, waves 0..1 also wid+6.
//  * Per iter: barrier -> pe4[3] loads (BEFORE DMAs so pe's vmcnt wait
//    leaves DMAs in flight) -> STAGE(kt+1, buf^1) -> compute buf.
#define KT 48
#define OS_LD 72
__global__ __launch_bounds__(384, 3) void attn(const bf16* __restrict__ Qp, const bf16* __restrict__ Kp,
                                               const bf16* __restrict__ Vt, const float* __restrict__ pe,
                                               bf16* __restrict__ O) {
    __shared__ bf16 Ks[2][KT*64];    // 2 x 6144 B
    __shared__ bf16 Vs[2][64*64];    // 2 x 8192 B
    const int tid  = threadIdx.x;
    const int lane = tid & 63, wid = tid >> 6;   // 6 waves
    const int bh   = blockIdx.y;
    const int b    = bh >> 4, h = bh & 15;
    const int qblk = blockIdx.x * 96;
    const int lm   = lane & 15, lq = lane >> 4;
    const int qbase = bh * (N_ * 64);

    // K staging: window = 8 rows x 8 chunks; lane -> row lane>>3, phys chunk
    // lane&7, fetched logical chunk (lane&7)^(lane>>3).
    const int kROff = (lane >> 3)*64 + ((lane & 7) ^ (lane >> 3))*8;
    // V staging: same lane pattern, logical chunk clamped to 5 (pad slots
    // duplicate chunk 5; readers never map logical c<=5 to a pad slot).
    int cV = (lane & 7) ^ (lane >> 3);
    if (cV > 5) cV = 5;
    int vOffG[2];
#pragma unroll
    for (int i = 0; i < 2; ++i) {
        int j = wid + 6*i;                       // window 0..7 (i=1 only wid<2)
        vOffG[i] = (bh*64 + j*8 + (lane >> 3))*480 + cV*8;
    }

    // Q fragments (B operand): n=q=lm, k=d
    bf16x8 qb[2];
#pragma unroll
    for (int ks = 0; ks < 2; ++ks)
        qb[ks] = *(const bf16x8*)&Qp[qbase + (qblk + wid*16 + lm)*64 + ks*32 + lq*8];
    const float* peP = pe + (qblk + wid*16 + lm)*480 + lq*4;

    // fragment LDS byte offsets (swizzle folded in)
    int kOff[2];
#pragma unroll
    for (int ks = 0; ks < 2; ++ks) kOff[ks] = ((ks*4 + lq) ^ (lm & 7)) << 4;
    int vOff[3];
#pragma unroll
    for (int mf = 0; mf < 3; ++mf) {
        int c = 2*mf + (lq >> 1);                // logical chunk 0..5
        vOff[mf] = ((c ^ (lm & 7)) << 4) + (lq & 1)*8;
    }

#define STAGE(T, BUF)                                                         \
    {   gld_lds16(Kp + qbase + (T)*(KT*64) + wid*512 + kROff,                 \
                  (char*)Ks[BUF] + wid*1024);                                 \
        gld_lds16(Vt + vOffG[0] + (T)*KT, (char*)Vs[BUF] + wid*1024);         \
        if (wid < 2)                                                          \
            gld_lds16(Vt + vOffG[1] + (T)*KT, (char*)Vs[BUF] + (wid+6)*1024); }

    STAGE(0, 0);

    f32x4 ot[4] = {};      // O^T accum: m=d (4 frags), n=q
    float lsum = 0.f;

    for (int kt = 0; kt < 10; ++kt) {
        const int cur = kt & 1;
        __syncthreads();                       // drains tile-kt DMA (issued a full phase ago)
        // pe loads first (older than DMAs in vmcnt order -> their waits can't drain DMAs)
        f32x4 pe4[3];
#pragma unroll
        for (int mf = 0; mf < 3; ++mf)
            pe4[mf] = *(const f32x4*)(peP + kt*KT + mf*16);
        if (kt < 9) STAGE(kt + 1, cur ^ 1);    // latency hides under compute
        const char* KsB = (const char*)Ks[cur];
        const char* VsB = (const char*)Vs[cur];

        // S^T = K Q^T; P^T = exp(scale*S^T + pe) packed as 16x16x16 B-frags
        short4v pb[3];
#pragma unroll
        for (int mf = 0; mf < 3; ++mf) {
            f32x4 s = {};
#pragma unroll
            for (int ks = 0; ks < 2; ++ks) {
                bf16x8 ka = *(const bf16x8*)(KsB + (mf*16 + lm)*128 + kOff[ks]);
                s = __builtin_amdgcn_mfma_f32_16x16x32_bf16(ka, qb[ks], s, 0, 0, 0);
            }
            bf16x4 pv;
#pragma unroll
            for (int r = 0; r < 4; ++r) {
                float e = __expf(s[r] * 0.125f + pe4[mf][r]);
                lsum += e;
                pv[r] = (bf16)e;
            }
            pb[mf] = __builtin_bit_cast(short4v, pv);
        }

        // O^T += V^T P^T via 16x16x16 (A = V frags from swizzled Vs rows)
#pragma unroll
        for (int df = 0; df < 4; ++df) {
            const char* vrow = VsB + (df*16 + lm)*128;
#pragma unroll
            for (int mf = 0; mf < 3; ++mf) {
                short4v va = *(const short4v*)(vrow + vOff[mf]);
                ot[df] = __builtin_amdgcn_mfma_f32_16x16x16bf16_1k(va, pb[mf], ot[df], 0, 0, 0);
            }
        }
    }
#undef STAGE

    // softmax denom across the 4 lane-groups holding q=lm
    lsum += __shfl_xor(lsum, 16);
    lsum += __shfl_xor(lsum, 32);
    float rl = 1.f / lsum;

    // transpose O^T -> O via LDS (reuse Vs region: 96*72*2 = 13824 <= 16384)
    __syncthreads();
    bf16* Os = &Vs[0][0];  // [96 q][OS_LD]
#pragma unroll
    for (int df = 0; df < 4; ++df)
#pragma unroll
        for (int r = 0; r < 4; ++r)
            Os[(wid*16 + lm)*OS_LD + df*16 + lq*4 + r] = (bf16)(ot[df][r] * rl);
    __syncthreads();
    for (int c = tid; c < 768; c += 384) {
        int row = c >> 3, d0 = (c & 7) * 8;
        uint4 u = *(const uint4*)&Os[row*OS_LD + d0];
        *(uint4*)&O[(b*480 + qblk + row)*1024 + h*64 + d0] = u;
    }
}

// ---------------- output projection GEMM + bias ----------------
__global__ __launch_bounds__(256) void gemm_out(const bf16* __restrict__ A, const bf16* __restrict__ Bw,
                                                const float* __restrict__ bo, float* __restrict__ out) {
    __shared__ bf16 As[128*64];
    __shared__ bf16 Bs[128*64];
    GEMM_PRE();
    f32x4 acc[4][4] = {};
    GEMM_KLOOP(af[m], bfr[n]);
#pragma unroll
    for (int m = 0; m < 4; ++m)
#pragma unroll
        for (int n = 0; n < 4; ++n)
#pragma unroll
            for (int r = 0; r < 4; ++r) {
                int gm = m0 + wm*64 + m*16 + lq*4 + r;
                int gn = n0 + wn*64 + n*16 + lm;
                out[gm*1024 + gn] = acc[m][n][r] + bo[gn];
            }
}

// ---------------- launcher ----------------
extern "C" void kernel_launch(void* const* d_in, const int* in_sizes, int n_in,
                              void* d_out, int out_size, void* d_ws, size_t ws_size,
                              hipStream_t stream) {
    const float* q  = (const float*)d_in[0];
    const float* Wq = (const float*)d_in[1];
    const float* Wk = (const float*)d_in[2];
    const float* Wv = (const float*)d_in[3];
    const float* pe = (const float*)d_in[4];
    const float* Wo = (const float*)d_in[5];
    const float* bo = (const float*)d_in[6];
    float* out = (float*)d_out;

    char* ws = (char*)d_ws;
    bf16* Abf  = (bf16*)(ws);                         // q bf16 (M x 1024); reused as attn O buffer
    bf16* Wcat = (bf16*)(ws + 31457280);              // 3072 x 1024
    bf16* Wob  = (bf16*)(ws + 31457280 + 6291456);    // 1024 x 1024
    bf16* Qp   = (bf16*)(ws + 39845888);              // [bh][n][d]
    bf16* Kp   = (bf16*)(ws + 71303168);              // [bh][n][d]
    bf16* Vt   = (bf16*)(ws + 102760448);             // [bh][d][n]

    cvt4<<<(M_*DIM_/4 + 255)/256, 256, 0, stream>>>(q, Abf, M_*DIM_/4);
    cvtW<<<dim3(DIM_*DIM_/4/256, 4), 256, 0, stream>>>(Wq, Wk, Wv, Wo, Wcat, Wob);

    gemm_qkv<<<dim3(24, 120), 256, 0, stream>>>(Abf, Wcat, Qp, Kp, Vt);
    attn<<<dim3(5, 512), 384, 0, stream>>>(Qp, Kp, Vt, pe, Abf);
    gemm_out<<<dim3(8, 120), 256, 0, stream>>>(Abf, Wob, bo, out);
}